// Round 14
// baseline (163.075 us; speedup 1.0000x reference)
//
#include <hip/hip_runtime.h>
#include <stdint.h>
#include <math.h>

typedef __attribute__((ext_vector_type(8))) short short8b;   // bf16x8 MFMA frag
typedef __attribute__((ext_vector_type(4))) float f32x4;
typedef __attribute__((ext_vector_type(8))) unsigned short u16x8;
typedef __attribute__((ext_vector_type(4))) unsigned int u32x4;

#define S 768
#define DD 768
#define H 12
#define DH 64

static __device__ __forceinline__ unsigned short f2bf(float f) {
  union { float f; unsigned u; } v; v.f = f;
  unsigned u = v.u;
  u += 0x7FFFu + ((u >> 16) & 1u);   // RNE
  return (unsigned short)(u >> 16);
}
static __device__ __forceinline__ unsigned pack2(float a, float b) {
  return (unsigned)f2bf(a) | ((unsigned)f2bf(b) << 16);
}

static __device__ __forceinline__ void gload_lds16(const void* g, void* l) {
  __builtin_amdgcn_global_load_lds((const __attribute__((address_space(1))) void*)g,
                                   (__attribute__((address_space(3))) void*)l, 16, 0, 0);
}

// ===== cast fp32 -> bf16 for both HS and IC in one launch =====
__global__ __launch_bounds__(256) void cast2_kernel(const float* __restrict__ inA,
                                                    const float* __restrict__ inB,
                                                    unsigned short* __restrict__ outA,
                                                    unsigned short* __restrict__ outB, int n8) {
  int i = blockIdx.x * 256 + threadIdx.x;
  const float* in; unsigned short* out;
  if (i >= n8) { in = inB; out = outB; i -= n8; }
  else         { in = inA; out = outA; }
  const float4* p = (const float4*)in;
  float4 a = p[2*(size_t)i], b = p[2*(size_t)i + 1];
  u16x8 o;
  o[0] = f2bf(a.x); o[1] = f2bf(a.y); o[2] = f2bf(a.z); o[3] = f2bf(a.w);
  o[4] = f2bf(b.x); o[5] = f2bf(b.y); o[6] = f2bf(b.z); o[7] = f2bf(b.w);
  *(u16x8*)(out + 8*(size_t)i) = o;
}

// ===== weight transpose+cast: T[n][k] = bf16(W[k][n]), 768x768, z selects matrix =====
__global__ __launch_bounds__(256) void wtrans4_kernel(
    const float* __restrict__ W0, const float* __restrict__ W1,
    const float* __restrict__ W2, const float* __restrict__ W3,
    unsigned short* __restrict__ T0, unsigned short* __restrict__ T1,
    unsigned short* __restrict__ T2, unsigned short* __restrict__ T3) {
  int z = blockIdx.z;
  const float* W = (z == 0) ? W0 : (z == 1) ? W1 : (z == 2) ? W2 : W3;
  unsigned short* T = (z == 0) ? T0 : (z == 1) ? T1 : (z == 2) ? T2 : T3;
  __shared__ float t[32][33];
  int tx = threadIdx.x & 31, ty = threadIdx.x >> 5;
  int k0 = blockIdx.x * 32, n0 = blockIdx.y * 32;
#pragma unroll
  for (int i = 0; i < 4; i++)
    t[ty + i*8][tx] = W[(size_t)(k0 + ty + i*8) * DD + n0 + tx];
  __syncthreads();
#pragma unroll
  for (int i = 0; i < 4; i++)
    T[(size_t)(n0 + ty + i*8) * DD + k0 + tx] = f2bf(t[tx][ty + i*8]);
}

// ===== gate[b,s,h] = sigmoid(HS @ Wg + bg), exact fp32 =====
__global__ __launch_bounds__(256) void gate_kernel(const float* __restrict__ HS,
                                                   const float* __restrict__ Wg,
                                                   const float* __restrict__ bg,
                                                   float* __restrict__ gate) {
  __shared__ float wgt[H][DD];   // 36 KB, transposed Wg
  int tid = threadIdx.x;
  for (int i = tid; i < DD*H; i += 256) {
    int d = i / H, h = i % H;
    wgt[h][d] = Wg[i];
  }
  __syncthreads();
  int w = tid >> 6, lane = tid & 63;
  int row0 = blockIdx.x * 16 + w * 4;
  for (int r = 0; r < 4; r++) {
    int row = row0 + r;
    const float* hrow = HS + (size_t)row * DD;
    float hv[12];
#pragma unroll
    for (int i = 0; i < 12; i++) hv[i] = hrow[lane + i*64];
    float acc[H];
#pragma unroll
    for (int h = 0; h < H; h++) {
      float s = 0.f;
#pragma unroll
      for (int i = 0; i < 12; i++) s += hv[i] * wgt[h][lane + i*64];
      acc[h] = s;
    }
#pragma unroll
    for (int m = 1; m < 64; m <<= 1) {
#pragma unroll
      for (int h = 0; h < H; h++) acc[h] += __shfl_xor(acc[h], m);
    }
    if (lane < H) {
      float v = 0.f;
#pragma unroll
      for (int h = 0; h < H; h++) v = (lane == h) ? acc[h] : v;  // static-index select
      v += bg[lane];
      gate[(size_t)row * H + lane] = 1.f / (1.f + __expf(-v));
    }
  }
}

// ===== 4-way GEMM: gload_lds staging, DOUBLE-BUFFERED, 1 sync per K-iter =====
__global__ __launch_bounds__(256) void gemm4_kernel(
    const unsigned short* __restrict__ HSb, const unsigned short* __restrict__ ICb,
    const unsigned short* __restrict__ WqT, const unsigned short* __restrict__ WkT,
    const unsigned short* __restrict__ WvT, const unsigned short* __restrict__ WaT,
    const float* __restrict__ bq, const float* __restrict__ bk,
    const float* __restrict__ bv, const float* __restrict__ ba,
    unsigned short* __restrict__ Qb, unsigned short* __restrict__ Kb,
    unsigned short* __restrict__ Vt, float* __restrict__ alignf) {
  int id = blockIdx.x;
  int wid = (id & 7) * 144 + (id >> 3);   // bijective XCD chunking (1152 % 8 == 0)
  int z = wid / 288;
  int rr = wid % 288;
  int bx = rr / 6, by = rr % 6;
  int m0 = bx * 128, n0 = by * 128;

  const unsigned short* A  = (z == 3) ? ICb : HSb;
  const unsigned short* BT = (z == 0) ? WqT : (z == 1) ? WkT : (z == 2) ? WvT : WaT;
  const float* bias = (z == 0) ? bq : (z == 1) ? bk : (z == 2) ? bv : ba;
  unsigned short* Cb = (z == 0) ? Qb : (z == 1) ? Kb : (unsigned short*)0;

  __shared__ __align__(16) char smem[65536];   // 2 x (As 16K + Bs 16K)

  int tid = threadIdx.x;
  int w = tid >> 6, lane = tid & 63;
  int cl = lane & 15, g = lane >> 4;
  int wm = (w & 1) * 64, wn = (w >> 1) * 64;

  f32x4 acc[4][4];
#pragma unroll
  for (int r = 0; r < 4; r++)
#pragma unroll
    for (int c = 0; c < 4; c++) acc[r][c] = (f32x4){0.f, 0.f, 0.f, 0.f};

  int srow = (lane >> 3) + w * 8;   // staging row within 32-row group
  int slot = lane & 7;              // 16B slot within 128B row

  auto stage = [&](int buf, int ks) {
    char* ad = smem + buf * 32768;
    char* bd = ad + 16384;
#pragma unroll
    for (int i = 0; i < 4; i++) {
      int row = i*32 + srow;
      gload_lds16(A  + (size_t)(m0 + row)*DD + ks + slot*8, ad + i*4096 + w*1024);
      gload_lds16(BT + (size_t)(n0 + row)*DD + ks + slot*8, bd + i*4096 + w*1024);
    }
  };

  stage(0, 0);
  __syncthreads();   // prologue drain
  for (int t = 0; t < 12; ++t) {
    int cur = t & 1;
    if (t + 1 < 12) stage(cur ^ 1, (t + 1) * 64);
    const char* As = smem + cur * 32768;
    const char* Bs = As + 16384;
#pragma unroll
    for (int kk = 0; kk < 2; kk++) {
      short8b af[4], bf[4];
#pragma unroll
      for (int r = 0; r < 4; r++) {
        int row = wm + r*16 + cl;
        af[r] = *(const short8b*)(As + row*128 + kk*64 + g*16);
      }
#pragma unroll
      for (int c = 0; c < 4; c++) {
        int row = wn + c*16 + cl;
        bf[c] = *(const short8b*)(Bs + row*128 + kk*64 + g*16);
      }
#pragma unroll
      for (int r = 0; r < 4; r++)
#pragma unroll
        for (int c = 0; c < 4; c++)
          acc[r][c] = __builtin_amdgcn_mfma_f32_16x16x32_bf16(af[r], bf[c], acc[r][c], 0, 0, 0);
    }
    __syncthreads();   // next tile's loads drained under this iter's compute
  }

  // ===== staged epilogue (regular stores: keep outputs cache-resident) =====
  if (z <= 1) {
#pragma unroll
    for (int c = 0; c < 4; c++) {
      int col = wn + c*16 + cl;
      float bvv = bias[n0 + col];
#pragma unroll
      for (int r = 0; r < 4; r++) {
#pragma unroll
        for (int q = 0; q < 4; q++) {
          int row = wm + r*16 + g*4 + q;
          int byte = (row*256 + col*2) ^ ((row & 7) << 4);
          *(unsigned short*)(smem + byte) = f2bf(acc[r][c][q] + bvv);
        }
      }
    }
    __syncthreads();
#pragma unroll
    for (int it = 0; it < 8; it++) {
      int idx = it*256 + tid;
      int row = idx >> 4, ch = idx & 15;
      u32x4 v = *(const u32x4*)(smem + ((row*256 + ch*16) ^ ((row & 7) << 4)));
      *(u32x4*)(Cb + (size_t)(m0 + row)*DD + n0 + ch*8) = v;
    }
  } else if (z == 2) {
#pragma unroll
    for (int c = 0; c < 4; c++) {
      int col = wn + c*16 + cl;
      float bvv = bias[n0 + col];
#pragma unroll
      for (int r = 0; r < 4; r++) {
#pragma unroll
        for (int q = 0; q < 4; q++) {
          int row = wm + r*16 + g*4 + q;
          int byte = (col*256 + row*2) ^ ((col & 7) << 4);
          *(unsigned short*)(smem + byte) = f2bf(acc[r][c][q] + bvv);
        }
      }
    }
    __syncthreads();
    int b = m0 / S, s0 = m0 % S;
#pragma unroll
    for (int it = 0; it < 8; it++) {
      int idx = it*256 + tid;
      int row = idx >> 4, ch = idx & 15;
      u32x4 v = *(const u32x4*)(smem + ((row*256 + ch*16) ^ ((row & 7) << 4)));
      *(u32x4*)(Vt + (size_t)(b*DD + n0 + row)*S + s0 + ch*8) = v;
    }
  } else {
#pragma unroll
    for (int half = 0; half < 2; half++) {
      if ((w & 1) == half) {
#pragma unroll
        for (int c = 0; c < 4; c++) {
          int col = wn + c*16 + cl;
          float bvv = bias[n0 + col];
#pragma unroll
          for (int r = 0; r < 4; r++) {
#pragma unroll
            for (int q = 0; q < 4; q++) {
              int rl = r*16 + g*4 + q;
              int byte = (rl*512 + col*4) ^ ((rl & 7) << 4);
              *(float*)(smem + byte) = acc[r][c][q] + bvv;
            }
          }
        }
      }
      __syncthreads();
#pragma unroll
      for (int it = 0; it < 8; it++) {
        int idx = it*256 + tid;
        int row = idx >> 5, ch = idx & 31;
        u32x4 v = *(const u32x4*)(smem + ((row*512 + ch*16) ^ ((row & 7) << 4)));
        *(u32x4*)(alignf + (size_t)(m0 + half*64 + row)*DD + n0 + ch*4) = v;
      }
      __syncthreads();
    }
  }
}

// ===== fused attention: unnormalized-exp bf16-packed (no max pass) =====
// logits: s = gate[b,h,q]*(q.k/8) + align[b,q,k]; |s| <~ 5 so exp(s) is safe
// unshifted. p = e/sum exactly; ctx scaled by 1/sum at epilogue (linearity).
__global__ __launch_bounds__(256) void attn_kernel(const unsigned short* __restrict__ Qb,
                                                   const unsigned short* __restrict__ Kb,
                                                   const unsigned short* __restrict__ Vt,
                                                   const float* __restrict__ alignf,
                                                   const float* __restrict__ gate,
                                                   float* __restrict__ ctx,
                                                   float* __restrict__ probs) {
  __shared__ __align__(16) char smemA[16384];             // p1: K dbuf | p2: V slab | epi: ctxs
  __shared__ __align__(16) unsigned short Ps[2][32*64];   // 8 KB P stage
  __shared__ float ssm[4][16];

  int tid = threadIdx.x;
  int w = tid >> 6, lane = tid & 63;
  int cl = lane & 15, g = lane >> 4;
  int id = blockIdx.x;
  int b = id & 7, t = id >> 3;
  int h = t % H, q0 = (t / H) * 32;
  int bh = b * H + h;
  int trow = (w >> 1) * 16;   // local q offset: 0 or 16
  int tc0 = (w & 1) * 2;      // this wave's 2 tile-cols (of 4)

  short8b qf[2];
  {
    const unsigned short* qp = Qb + (size_t)(b*S + q0 + trow + cl)*DD + h*DH + g*8;
    qf[0] = *(const short8b*)qp;
    qf[1] = *(const short8b*)(qp + 32);
  }
  f32x4 g4v;
#pragma unroll
  for (int r = 0; r < 4; r++)
    g4v[r] = gate[(size_t)(b*S + q0 + trow + g*4 + r)*H + h] * 0.125f;

  const unsigned short* kbase = Kb + (size_t)b*S*DD + h*DH;
  const unsigned short* vbase = Vt + (size_t)bh*DH*S;
  const float* abase = alignf + (size_t)(b*S + q0 + trow + g*4)*S;

  int srow = (lane >> 3) + w * 8;   // staging row within 32-row group
  int slot = lane & 7;              // 16B slot within 128B row
  auto stageK = [&](int buf, int k0) {
    char* dst = smemA + buf * 8192;
#pragma unroll
    for (int i = 0; i < 2; i++) {
      int row = i*32 + srow;
      gload_lds16(kbase + (size_t)(k0 + row)*DD + slot*8, dst + i*4096 + w*1024);
    }
  };

  // ---- pass 1: K staged ahead; exp immediately; pack e to bf16 pairs ----
  unsigned pe[12][4];          // 48 regs (was 96 f32)
  float sum4[4] = {0.f, 0.f, 0.f, 0.f};
  stageK(0, 0);
  __syncthreads();
#pragma unroll
  for (int c = 0; c < 12; c++) {
    int k0 = c * 64;
    if (c + 1 < 12) stageK((c + 1) & 1, k0 + 64);
    const char* Ks = smemA + (c & 1) * 8192;
    f32x4 sc0 = (f32x4){0.f,0.f,0.f,0.f}, sc1 = (f32x4){0.f,0.f,0.f,0.f};
#pragma unroll
    for (int kk = 0; kk < 2; kk++) {
      int r0 = tc0*16 + cl;
      sc0 = __builtin_amdgcn_mfma_f32_16x16x32_bf16(qf[kk], *(const short8b*)(Ks + r0*128 + kk*64 + g*16), sc0, 0, 0, 0);
      sc1 = __builtin_amdgcn_mfma_f32_16x16x32_bf16(qf[kk], *(const short8b*)(Ks + (r0+16)*128 + kk*64 + g*16), sc1, 0, 0, 0);
    }
    f32x4 a0, a1;
#pragma unroll
    for (int r = 0; r < 4; r++) {
      a0[r] = abase[(size_t)r*S + k0 + tc0*16 + cl];
      a1[r] = abase[(size_t)r*S + k0 + tc0*16 + 16 + cl];
    }
#pragma unroll
    for (int r = 0; r < 4; r++) {
      float e0 = __expf(sc0[r] * g4v[r] + a0[r]);
      float e1 = __expf(sc1[r] * g4v[r] + a1[r]);
      sum4[r] += e0 + e1;
      pe[c][r] = pack2(e0, e1);
    }
    __syncthreads();   // next chunk's K staged under this chunk's compute
  }

  // ---- sum reduce (no max pass needed) ----
  float ssr[4];
#pragma unroll
  for (int r = 0; r < 4; r++) {
    float s = sum4[r];
    s += __shfl_xor(s, 1);
    s += __shfl_xor(s, 2);
    s += __shfl_xor(s, 4);
    s += __shfl_xor(s, 8);
    sum4[r] = s;
  }
  if (cl == 0) {
#pragma unroll
    for (int r = 0; r < 4; r++) ssm[w][g*4 + r] = sum4[r];
  }
  __syncthreads();
#pragma unroll
  for (int r = 0; r < 4; r++) ssr[r] = 1.f / (sum4[r] + ssm[w ^ 1][g*4 + r]);

  // ---- pass 2: 6 super-iterations of 2 chunks; V staged; probs in PV phase ----
  f32x4 oc0 = (f32x4){0.f,0.f,0.f,0.f}, oc1 = (f32x4){0.f,0.f,0.f,0.f};
#pragma unroll
  for (int tt = 0; tt < 6; tt++) {
    // stage V[d=0..63][k = tt*128 .. +128) -> linear [64][256B]
#pragma unroll
    for (int i = 0; i < 4; i++) {
      int u = i*256 + tid;
      int row = u >> 4, sl = u & 15;
      gload_lds16(vbase + (size_t)row*S + tt*128 + sl*8, smemA + i*4096 + w*1024);
    }
    // fill Ps: pure unpack + LDS writes (no float math)
#pragma unroll
    for (int j = 0; j < 2; j++) {
      int c = tt*2 + j;
#pragma unroll
      for (int r = 0; r < 4; r++) {
        int ql = trow + g*4 + r;
        unsigned pk = pe[c][r];
        int off0 = (ql*128 + (tc0*16 + cl)*2) ^ ((ql & 7) << 4);
        int off1 = (ql*128 + (tc0*16 + 16 + cl)*2) ^ ((ql & 7) << 4);
        *(unsigned short*)((char*)Ps[j] + off0) = (unsigned short)pk;
        *(unsigned short*)((char*)Ps[j] + off1) = (unsigned short)(pk >> 16);
      }
    }
    __syncthreads();   // V slab + Ps writes drained
    // PV phase: probs nt-stores (bf16 e * ssr) interleaved with MFMAs
#pragma unroll
    for (int j = 0; j < 2; j++) {
      int c = tt*2 + j;
      int k0 = c * 64;
#pragma unroll
      for (int r = 0; r < 4; r++) {
        int ql = trow + g*4 + r;
        unsigned pk = pe[c][r];
        union { unsigned u; float f; } lo, hi;
        lo.u = pk << 16;
        hi.u = pk & 0xffff0000u;
        float* pr = probs + ((size_t)bh*S + q0 + ql)*S + k0;
        __builtin_nontemporal_store(lo.f * ssr[r], pr + tc0*16 + cl);
        __builtin_nontemporal_store(hi.f * ssr[r], pr + tc0*16 + 16 + cl);
      }
#pragma unroll
      for (int kk = 0; kk < 2; kk++) {
        int prow = trow + cl;
        int po = (prow*128 + kk*64 + g*16) ^ ((prow & 7) << 4);
        short8b pf = *(const short8b*)((const char*)Ps[j] + po);
        int d0 = tc0*16 + cl;
        oc0 = __builtin_amdgcn_mfma_f32_16x16x32_bf16(pf, *(const short8b*)(smemA + d0*256 + j*128 + kk*64 + g*16), oc0, 0, 0, 0);
        oc1 = __builtin_amdgcn_mfma_f32_16x16x32_bf16(pf, *(const short8b*)(smemA + (d0+16)*256 + j*128 + kk*64 + g*16), oc1, 0, 0, 0);
      }
    }
    __syncthreads();   // V slab fully consumed
  }

  // ---- ctx epilogue: scale by 1/sum here (PV used unnormalized e) ----
  float* ctxs = (float*)smemA;
#pragma unroll
  for (int r = 0; r < 4; r++) {
    int ql = trow + g*4 + r;
    ctxs[ql*68 + tc0*16 + cl]      = oc0[r] * ssr[r];
    ctxs[ql*68 + tc0*16 + 16 + cl] = oc1[r] * ssr[r];
  }
  __syncthreads();
#pragma unroll
  for (int j = 0; j < 2; j++) {
    int idx = tid + j*256;
    int row = idx >> 4, c4 = idx & 15;
    f32x4 v = *(const f32x4*)(ctxs + row*68 + c4*4);
    __builtin_nontemporal_store(v, (f32x4*)(ctx + (size_t)(b*S + q0 + row)*DD + h*DH + c4*4));
  }
}

extern "C" void kernel_launch(void* const* d_in, const int* in_sizes, int n_in,
                              void* d_out, int out_size, void* d_ws, size_t ws_size,
                              hipStream_t stream) {
  const float* HS = (const float*)d_in[0];
  const float* IC = (const float*)d_in[1];
  const float* Wq = (const float*)d_in[2];
  const float* bq = (const float*)d_in[3];
  const float* Wk = (const float*)d_in[4];
  const float* bk = (const float*)d_in[5];
  const float* Wv = (const float*)d_in[6];
  const float* bv = (const float*)d_in[7];
  // d_in[8] = Wcs, d_in[9] = bcs: provably cancel in softmax -> unused
  const float* Wg = (const float*)d_in[10];
  const float* bg = (const float*)d_in[11];
  const float* Wa = (const float*)d_in[12];
  const float* ba = (const float*)d_in[13];

  float* ctx   = (float*)d_out;
  float* probs = ctx + (size_t)8 * S * DD;

  char* ws = (char*)d_ws;
  size_t off = 0;
  auto alloc = [&](size_t n) { char* p = ws + off; off += (n + 255) & ~(size_t)255; return p; };
  unsigned short* HSb = (unsigned short*)alloc(9437184);
  unsigned short* ICb = (unsigned short*)alloc(9437184);
  unsigned short* WqT = (unsigned short*)alloc(1179648);
  unsigned short* WkT = (unsigned short*)alloc(1179648);
  unsigned short* WvT = (unsigned short*)alloc(1179648);
  unsigned short* WaT = (unsigned short*)alloc(1179648);
  unsigned short* Qb  = (unsigned short*)alloc(9437184);
  unsigned short* Kb  = (unsigned short*)alloc(9437184);
  unsigned short* Vt  = (unsigned short*)alloc(9437184);
  float* alignf = (float*)alloc(18874368);
  float* gatep  = (float*)alloc(294912);

  int n8 = 8 * S * DD / 8;
  cast2_kernel<<<dim3((2*n8 + 255) / 256), dim3(256), 0, stream>>>(HS, IC, HSb, ICb, n8);
  wtrans4_kernel<<<dim3(24, 24, 4), dim3(256), 0, stream>>>(Wq, Wk, Wv, Wa, WqT, WkT, WvT, WaT);
  gemm4_kernel<<<dim3(1152), dim3(256), 0, stream>>>(HSb, ICb, WqT, WkT, WvT, WaT,
                                                     bq, bk, bv, ba, Qb, Kb, Vt, alignf);
  gate_kernel<<<dim3(384), dim3(256), 0, stream>>>(HS, Wg, bg, gatep);
  attn_kernel<<<dim3(2304), dim3(256), 0, stream>>>(Qb, Kb, Vt, alignf, gatep, ctx, probs);
}

// Round 15
// 149.725 us; speedup vs baseline: 1.0892x; 1.0892x over previous
//
#include <hip/hip_runtime.h>
#include <stdint.h>
#include <math.h>

typedef __attribute__((ext_vector_type(8))) short short8b;   // bf16x8 MFMA frag
typedef __attribute__((ext_vector_type(4))) float f32x4;
typedef __attribute__((ext_vector_type(8))) unsigned short u16x8;
typedef __attribute__((ext_vector_type(4))) unsigned int u32x4;

#define S 768
#define DD 768
#define H 12
#define DH 64

static __device__ __forceinline__ unsigned short f2bf(float f) {
  union { float f; unsigned u; } v; v.f = f;
  unsigned u = v.u;
  u += 0x7FFFu + ((u >> 16) & 1u);   // RNE
  return (unsigned short)(u >> 16);
}

static __device__ __forceinline__ void gload_lds16(const void* g, void* l) {
  __builtin_amdgcn_global_load_lds((const __attribute__((address_space(1))) void*)g,
                                   (__attribute__((address_space(3))) void*)l, 16, 0, 0);
}

// ===== merged prep: blocks [0,4608) cast HS/IC -> bf16; [4608,6912) transpose W =====
__global__ __launch_bounds__(256) void prep_kernel(
    const float* __restrict__ HS, const float* __restrict__ IC,
    const float* __restrict__ W0, const float* __restrict__ W1,
    const float* __restrict__ W2, const float* __restrict__ W3,
    unsigned short* __restrict__ HSb, unsigned short* __restrict__ ICb,
    unsigned short* __restrict__ T0, unsigned short* __restrict__ T1,
    unsigned short* __restrict__ T2, unsigned short* __restrict__ T3, int n8) {
  __shared__ float t[32][33];
  int id = blockIdx.x;
  int tid = threadIdx.x;
  if (id < 4608) {
    int i = id * 256 + tid;
    const float* in; unsigned short* out;
    if (i >= n8) { in = IC; out = ICb; i -= n8; }
    else         { in = HS; out = HSb; }
    const float4* p = (const float4*)in;
    float4 a = p[2*(size_t)i], b = p[2*(size_t)i + 1];
    u16x8 o;
    o[0] = f2bf(a.x); o[1] = f2bf(a.y); o[2] = f2bf(a.z); o[3] = f2bf(a.w);
    o[4] = f2bf(b.x); o[5] = f2bf(b.y); o[6] = f2bf(b.z); o[7] = f2bf(b.w);
    *(u16x8*)(out + 8*(size_t)i) = o;
    return;
  }
  int wid = id - 4608;
  int z = wid / 576;
  int r = wid % 576;
  int k0 = (r % 24) * 32, n0 = (r / 24) * 32;
  const float* W = (z == 0) ? W0 : (z == 1) ? W1 : (z == 2) ? W2 : W3;
  unsigned short* T = (z == 0) ? T0 : (z == 1) ? T1 : (z == 2) ? T2 : T3;
  int tx = tid & 31, ty = tid >> 5;
#pragma unroll
  for (int i = 0; i < 4; i++)
    t[ty + i*8][tx] = W[(size_t)(k0 + ty + i*8) * DD + n0 + tx];
  __syncthreads();
#pragma unroll
  for (int i = 0; i < 4; i++)
    T[(size_t)(n0 + ty + i*8) * DD + k0 + tx] = f2bf(t[tx][ty + i*8]);
}

// ===== gate[b,s,h] = sigmoid(HS @ Wg + bg), exact fp32 =====
__global__ __launch_bounds__(256) void gate_kernel(const float* __restrict__ HS,
                                                   const float* __restrict__ Wg,
                                                   const float* __restrict__ bg,
                                                   float* __restrict__ gate) {
  __shared__ float wgt[H][DD];   // 36 KB, transposed Wg
  int tid = threadIdx.x;
  for (int i = tid; i < DD*H; i += 256) {
    int d = i / H, h = i % H;
    wgt[h][d] = Wg[i];
  }
  __syncthreads();
  int w = tid >> 6, lane = tid & 63;
  int row0 = blockIdx.x * 16 + w * 4;
  for (int r = 0; r < 4; r++) {
    int row = row0 + r;
    const float* hrow = HS + (size_t)row * DD;
    float hv[12];
#pragma unroll
    for (int i = 0; i < 12; i++) hv[i] = hrow[lane + i*64];
    float acc[H];
#pragma unroll
    for (int h = 0; h < H; h++) {
      float s = 0.f;
#pragma unroll
      for (int i = 0; i < 12; i++) s += hv[i] * wgt[h][lane + i*64];
      acc[h] = s;
    }
#pragma unroll
    for (int m = 1; m < 64; m <<= 1) {
#pragma unroll
      for (int h = 0; h < H; h++) acc[h] += __shfl_xor(acc[h], m);
    }
    if (lane < H) {
      float v = 0.f;
#pragma unroll
      for (int h = 0; h < H; h++) v = (lane == h) ? acc[h] : v;  // static-index select
      v += bg[lane];
      gate[(size_t)row * H + lane] = 1.f / (1.f + __expf(-v));
    }
  }
}

// ===== 4-way GEMM: gload_lds staging, DOUBLE-BUFFERED, 1 sync per K-iter =====
__global__ __launch_bounds__(256) void gemm4_kernel(
    const unsigned short* __restrict__ HSb, const unsigned short* __restrict__ ICb,
    const unsigned short* __restrict__ WqT, const unsigned short* __restrict__ WkT,
    const unsigned short* __restrict__ WvT, const unsigned short* __restrict__ WaT,
    const float* __restrict__ bq, const float* __restrict__ bk,
    const float* __restrict__ bv, const float* __restrict__ ba,
    unsigned short* __restrict__ Qb, unsigned short* __restrict__ Kb,
    unsigned short* __restrict__ Vt, float* __restrict__ alignf) {
  int id = blockIdx.x;
  int wid = (id & 7) * 144 + (id >> 3);   // bijective XCD chunking (1152 % 8 == 0)
  int z = wid / 288;
  int rr = wid % 288;
  int bx = rr / 6, by = rr % 6;
  int m0 = bx * 128, n0 = by * 128;

  const unsigned short* A  = (z == 3) ? ICb : HSb;
  const unsigned short* BT = (z == 0) ? WqT : (z == 1) ? WkT : (z == 2) ? WvT : WaT;
  const float* bias = (z == 0) ? bq : (z == 1) ? bk : (z == 2) ? bv : ba;
  unsigned short* Cb = (z == 0) ? Qb : (z == 1) ? Kb : (unsigned short*)0;

  __shared__ __align__(16) char smem[65536];   // 2 x (As 16K + Bs 16K)

  int tid = threadIdx.x;
  int w = tid >> 6, lane = tid & 63;
  int cl = lane & 15, g = lane >> 4;
  int wm = (w & 1) * 64, wn = (w >> 1) * 64;

  f32x4 acc[4][4];
#pragma unroll
  for (int r = 0; r < 4; r++)
#pragma unroll
    for (int c = 0; c < 4; c++) acc[r][c] = (f32x4){0.f, 0.f, 0.f, 0.f};

  int srow = (lane >> 3) + w * 8;   // staging row within 32-row group
  int slot = lane & 7;              // 16B slot within 128B row

  auto stage = [&](int buf, int ks) {
    char* ad = smem + buf * 32768;
    char* bd = ad + 16384;
#pragma unroll
    for (int i = 0; i < 4; i++) {
      int row = i*32 + srow;
      gload_lds16(A  + (size_t)(m0 + row)*DD + ks + slot*8, ad + i*4096 + w*1024);
      gload_lds16(BT + (size_t)(n0 + row)*DD + ks + slot*8, bd + i*4096 + w*1024);
    }
  };

  stage(0, 0);
  __syncthreads();   // prologue drain
  for (int t = 0; t < 12; ++t) {
    int cur = t & 1;
    if (t + 1 < 12) stage(cur ^ 1, (t + 1) * 64);
    const char* As = smem + cur * 32768;
    const char* Bs = As + 16384;
#pragma unroll
    for (int kk = 0; kk < 2; kk++) {
      short8b af[4], bf[4];
#pragma unroll
      for (int r = 0; r < 4; r++) {
        int row = wm + r*16 + cl;
        af[r] = *(const short8b*)(As + row*128 + kk*64 + g*16);
      }
#pragma unroll
      for (int c = 0; c < 4; c++) {
        int row = wn + c*16 + cl;
        bf[c] = *(const short8b*)(Bs + row*128 + kk*64 + g*16);
      }
#pragma unroll
      for (int r = 0; r < 4; r++)
#pragma unroll
        for (int c = 0; c < 4; c++)
          acc[r][c] = __builtin_amdgcn_mfma_f32_16x16x32_bf16(af[r], bf[c], acc[r][c], 0, 0, 0);
    }
    __syncthreads();   // next tile's loads drained under this iter's compute
  }

  // ===== staged epilogue (regular stores: keep outputs cache-resident) =====
  if (z <= 1) {
#pragma unroll
    for (int c = 0; c < 4; c++) {
      int col = wn + c*16 + cl;
      float bvv = bias[n0 + col];
#pragma unroll
      for (int r = 0; r < 4; r++) {
#pragma unroll
        for (int q = 0; q < 4; q++) {
          int row = wm + r*16 + g*4 + q;
          int byte = (row*256 + col*2) ^ ((row & 7) << 4);
          *(unsigned short*)(smem + byte) = f2bf(acc[r][c][q] + bvv);
        }
      }
    }
    __syncthreads();
#pragma unroll
    for (int it = 0; it < 8; it++) {
      int idx = it*256 + tid;
      int row = idx >> 4, ch = idx & 15;
      u32x4 v = *(const u32x4*)(smem + ((row*256 + ch*16) ^ ((row & 7) << 4)));
      *(u32x4*)(Cb + (size_t)(m0 + row)*DD + n0 + ch*8) = v;
    }
  } else if (z == 2) {
#pragma unroll
    for (int c = 0; c < 4; c++) {
      int col = wn + c*16 + cl;
      float bvv = bias[n0 + col];
#pragma unroll
      for (int r = 0; r < 4; r++) {
#pragma unroll
        for (int q = 0; q < 4; q++) {
          int row = wm + r*16 + g*4 + q;
          int byte = (col*256 + row*2) ^ ((col & 7) << 4);
          *(unsigned short*)(smem + byte) = f2bf(acc[r][c][q] + bvv);
        }
      }
    }
    __syncthreads();
    int b = m0 / S, s0 = m0 % S;
#pragma unroll
    for (int it = 0; it < 8; it++) {
      int idx = it*256 + tid;
      int row = idx >> 4, ch = idx & 15;
      u32x4 v = *(const u32x4*)(smem + ((row*256 + ch*16) ^ ((row & 7) << 4)));
      *(u32x4*)(Vt + (size_t)(b*DD + n0 + row)*S + s0 + ch*8) = v;
    }
  } else {
#pragma unroll
    for (int half = 0; half < 2; half++) {
      if ((w & 1) == half) {
#pragma unroll
        for (int c = 0; c < 4; c++) {
          int col = wn + c*16 + cl;
          float bvv = bias[n0 + col];
#pragma unroll
          for (int r = 0; r < 4; r++) {
#pragma unroll
            for (int q = 0; q < 4; q++) {
              int rl = r*16 + g*4 + q;
              int byte = (rl*512 + col*4) ^ ((rl & 7) << 4);
              *(float*)(smem + byte) = acc[r][c][q] + bvv;
            }
          }
        }
      }
      __syncthreads();
#pragma unroll
      for (int it = 0; it < 8; it++) {
        int idx = it*256 + tid;
        int row = idx >> 5, ch = idx & 31;
        u32x4 v = *(const u32x4*)(smem + ((row*512 + ch*16) ^ ((row & 7) << 4)));
        *(u32x4*)(alignf + (size_t)(m0 + half*64 + row)*DD + n0 + ch*4) = v;
      }
      __syncthreads();
    }
  }
}

// ===== fused attention (R13): K/V staged via gload_lds; probs stores in PV phase =====
// logits: s = gate[b,h,q]*(q.k/8) + align[b,q,k]   (cs term cancels in softmax)
__global__ __launch_bounds__(256) void attn_kernel(const unsigned short* __restrict__ Qb,
                                                   const unsigned short* __restrict__ Kb,
                                                   const unsigned short* __restrict__ Vt,
                                                   const float* __restrict__ alignf,
                                                   const float* __restrict__ gate,
                                                   float* __restrict__ ctx,
                                                   float* __restrict__ probs) {
  __shared__ __align__(16) char smemA[16384];             // p1: K dbuf | p2: V slab | epi: ctxs
  __shared__ __align__(16) unsigned short Ps[2][32*64];   // 8 KB P stage
  __shared__ float smx[4][16], ssm[4][16];

  int tid = threadIdx.x;
  int w = tid >> 6, lane = tid & 63;
  int cl = lane & 15, g = lane >> 4;
  int id = blockIdx.x;
  int b = id & 7, t = id >> 3;
  int h = t % H, q0 = (t / H) * 32;
  int bh = b * H + h;
  int trow = (w >> 1) * 16;   // local q offset: 0 or 16
  int tc0 = (w & 1) * 2;      // this wave's 2 tile-cols (of 4)

  short8b qf[2];
  {
    const unsigned short* qp = Qb + (size_t)(b*S + q0 + trow + cl)*DD + h*DH + g*8;
    qf[0] = *(const short8b*)qp;
    qf[1] = *(const short8b*)(qp + 32);
  }
  f32x4 g4v;
#pragma unroll
  for (int r = 0; r < 4; r++)
    g4v[r] = gate[(size_t)(b*S + q0 + trow + g*4 + r)*H + h] * 0.125f;

  const unsigned short* kbase = Kb + (size_t)b*S*DD + h*DH;
  const unsigned short* vbase = Vt + (size_t)bh*DH*S;
  const float* abase = alignf + (size_t)(b*S + q0 + trow + g*4)*S;

  int srow = (lane >> 3) + w * 8;   // staging row within 32-row group
  int slot = lane & 7;              // 16B slot within 128B row
  auto stageK = [&](int buf, int k0) {
    char* dst = smemA + buf * 8192;
#pragma unroll
    for (int i = 0; i < 2; i++) {
      int row = i*32 + srow;
      gload_lds16(kbase + (size_t)(k0 + row)*DD + slot*8, dst + i*4096 + w*1024);
    }
  };

  // ---- pass 1: K staged ahead (stage next -> compute cur -> sync) ----
  f32x4 vs0[12], vs1[12];
  stageK(0, 0);
  __syncthreads();
#pragma unroll
  for (int c = 0; c < 12; c++) {
    int k0 = c * 64;
    if (c + 1 < 12) stageK((c + 1) & 1, k0 + 64);
    const char* Ks = smemA + (c & 1) * 8192;
    f32x4 sc0 = (f32x4){0.f,0.f,0.f,0.f}, sc1 = (f32x4){0.f,0.f,0.f,0.f};
#pragma unroll
    for (int kk = 0; kk < 2; kk++) {
      int r0 = tc0*16 + cl;
      sc0 = __builtin_amdgcn_mfma_f32_16x16x32_bf16(qf[kk], *(const short8b*)(Ks + r0*128 + kk*64 + g*16), sc0, 0, 0, 0);
      sc1 = __builtin_amdgcn_mfma_f32_16x16x32_bf16(qf[kk], *(const short8b*)(Ks + (r0+16)*128 + kk*64 + g*16), sc1, 0, 0, 0);
    }
    f32x4 a0, a1;
#pragma unroll
    for (int r = 0; r < 4; r++) {
      a0[r] = abase[(size_t)r*S + k0 + tc0*16 + cl];
      a1[r] = abase[(size_t)r*S + k0 + tc0*16 + 16 + cl];
    }
    vs0[c] = sc0 * g4v + a0;
    vs1[c] = sc1 * g4v + a1;
    __syncthreads();   // next chunk's K staged under this chunk's compute
  }

  // ---- deferred softmax over registers ----
  float m[4], ssr[4];
#pragma unroll
  for (int r = 0; r < 4; r++) {
    float mm = -INFINITY;
#pragma unroll
    for (int c = 0; c < 12; c++)
      mm = fmaxf(mm, fmaxf(vs0[c][r], vs1[c][r]));
    mm = fmaxf(mm, __shfl_xor(mm, 1));
    mm = fmaxf(mm, __shfl_xor(mm, 2));
    mm = fmaxf(mm, __shfl_xor(mm, 4));
    mm = fmaxf(mm, __shfl_xor(mm, 8));
    m[r] = mm;
  }
  if (cl == 0) {
#pragma unroll
    for (int r = 0; r < 4; r++) smx[w][g*4 + r] = m[r];
  }
  __syncthreads();
#pragma unroll
  for (int r = 0; r < 4; r++) m[r] = fmaxf(m[r], smx[w ^ 1][g*4 + r]);
  float sum[4];
#pragma unroll
  for (int r = 0; r < 4; r++) {
    float s = 0.f;
#pragma unroll
    for (int c = 0; c < 12; c++) {
      float e0 = __expf(vs0[c][r] - m[r]);
      float e1 = __expf(vs1[c][r] - m[r]);
      vs0[c][r] = e0;
      vs1[c][r] = e1;
      s += e0 + e1;
    }
    s += __shfl_xor(s, 1);
    s += __shfl_xor(s, 2);
    s += __shfl_xor(s, 4);
    s += __shfl_xor(s, 8);
    sum[r] = s;
  }
  if (cl == 0) {
#pragma unroll
    for (int r = 0; r < 4; r++) ssm[w][g*4 + r] = sum[r];
  }
  __syncthreads();
#pragma unroll
  for (int r = 0; r < 4; r++) ssr[r] = 1.f / (sum[r] + ssm[w ^ 1][g*4 + r]);

  // ---- pass 2: 6 super-iterations of 2 chunks; V slab staged; probs stores in PV phase ----
  f32x4 oc0 = (f32x4){0.f,0.f,0.f,0.f}, oc1 = (f32x4){0.f,0.f,0.f,0.f};
#pragma unroll
  for (int tt = 0; tt < 6; tt++) {
    // stage V[d=0..63][k = tt*128 .. +128) -> linear [64][256B]
#pragma unroll
    for (int i = 0; i < 4; i++) {
      int u = i*256 + tid;
      int row = u >> 4, sl = u & 15;
      gload_lds16(vbase + (size_t)row*S + tt*128 + sl*8, smemA + i*4096 + w*1024);
    }
    // fill Ps (LDS only) for chunks 2tt, 2tt+1
#pragma unroll
    for (int j = 0; j < 2; j++) {
      int c = tt*2 + j;
#pragma unroll
      for (int r = 0; r < 4; r++) {
        int ql = trow + g*4 + r;
        float p0 = vs0[c][r] * ssr[r];
        float p1 = vs1[c][r] * ssr[r];
        int off0 = (ql*128 + (tc0*16 + cl)*2) ^ ((ql & 7) << 4);
        int off1 = (ql*128 + (tc0*16 + 16 + cl)*2) ^ ((ql & 7) << 4);
        *(unsigned short*)((char*)Ps[j] + off0) = f2bf(p0);
        *(unsigned short*)((char*)Ps[j] + off1) = f2bf(p1);
      }
    }
    __syncthreads();   // V slab + Ps writes drained (V issued first, drains under fill)
    // PV phase: probs nt-stores interleaved with MFMAs (drain under compute)
#pragma unroll
    for (int j = 0; j < 2; j++) {
      int c = tt*2 + j;
      int k0 = c * 64;
#pragma unroll
      for (int r = 0; r < 4; r++) {
        int ql = trow + g*4 + r;
        float* pr = probs + ((size_t)bh*S + q0 + ql)*S + k0;
        __builtin_nontemporal_store(vs0[c][r] * ssr[r], pr + tc0*16 + cl);
        __builtin_nontemporal_store(vs1[c][r] * ssr[r], pr + tc0*16 + 16 + cl);
      }
#pragma unroll
      for (int kk = 0; kk < 2; kk++) {
        int prow = trow + cl;
        int po = (prow*128 + kk*64 + g*16) ^ ((prow & 7) << 4);
        short8b pf = *(const short8b*)((const char*)Ps[j] + po);
        int d0 = tc0*16 + cl;
        oc0 = __builtin_amdgcn_mfma_f32_16x16x32_bf16(pf, *(const short8b*)(smemA + d0*256 + j*128 + kk*64 + g*16), oc0, 0, 0, 0);
        oc1 = __builtin_amdgcn_mfma_f32_16x16x32_bf16(pf, *(const short8b*)(smemA + (d0+16)*256 + j*128 + kk*64 + g*16), oc1, 0, 0, 0);
      }
    }
    __syncthreads();   // V slab fully consumed; probs stores had PV compute to drain
  }

  // ---- ctx epilogue: stage in LDS (reusing smemA), stream f32x4 ----
  float* ctxs = (float*)smemA;
#pragma unroll
  for (int r = 0; r < 4; r++) {
    int ql = trow + g*4 + r;
    ctxs[ql*68 + tc0*16 + cl]      = oc0[r];
    ctxs[ql*68 + tc0*16 + 16 + cl] = oc1[r];
  }
  __syncthreads();
#pragma unroll
  for (int j = 0; j < 2; j++) {
    int idx = tid + j*256;
    int row = idx >> 4, c4 = idx & 15;
    f32x4 v = *(const f32x4*)(ctxs + row*68 + c4*4);
    __builtin_nontemporal_store(v, (f32x4*)(ctx + (size_t)(b*S + q0 + row)*DD + h*DH + c4*4));
  }
}

extern "C" void kernel_launch(void* const* d_in, const int* in_sizes, int n_in,
                              void* d_out, int out_size, void* d_ws, size_t ws_size,
                              hipStream_t stream) {
  const float* HS = (const float*)d_in[0];
  const float* IC = (const float*)d_in[1];
  const float* Wq = (const float*)d_in[2];
  const float* bq = (const float*)d_in[3];
  const float* Wk = (const float*)d_in[4];
  const float* bk = (const float*)d_in[5];
  const float* Wv = (const float*)d_in[6];
  const float* bv = (const float*)d_in[7];
  // d_in[8] = Wcs, d_in[9] = bcs: provably cancel in softmax -> unused
  const float* Wg = (const float*)d_in[10];
  const float* bg = (const float*)d_in[11];
  const float* Wa = (const float*)d_in[12];
  const float* ba = (const float*)d_in[13];

  float* ctx   = (float*)d_out;
  float* probs = ctx + (size_t)8 * S * DD;

  char* ws = (char*)d_ws;
  size_t off = 0;
  auto alloc = [&](size_t n) { char* p = ws + off; off += (n + 255) & ~(size_t)255; return p; };
  unsigned short* HSb = (unsigned short*)alloc(9437184);
  unsigned short* ICb = (unsigned short*)alloc(9437184);
  unsigned short* WqT = (unsigned short*)alloc(1179648);
  unsigned short* WkT = (unsigned short*)alloc(1179648);
  unsigned short* WvT = (unsigned short*)alloc(1179648);
  unsigned short* WaT = (unsigned short*)alloc(1179648);
  unsigned short* Qb  = (unsigned short*)alloc(9437184);
  unsigned short* Kb  = (unsigned short*)alloc(9437184);
  unsigned short* Vt  = (unsigned short*)alloc(9437184);
  float* alignf = (float*)alloc(18874368);
  float* gatep  = (float*)alloc(294912);

  int n8 = 8 * S * DD / 8;
  prep_kernel<<<dim3(6912), dim3(256), 0, stream>>>(HS, IC, Wq, Wk, Wv, Wa,
                                                    HSb, ICb, WqT, WkT, WvT, WaT, n8);
  gemm4_kernel<<<dim3(1152), dim3(256), 0, stream>>>(HSb, ICb, WqT, WkT, WvT, WaT,
                                                     bq, bk, bv, ba, Qb, Kb, Vt, alignf);
  gate_kernel<<<dim3(384), dim3(256), 0, stream>>>(HS, Wg, bg, gatep);
  attn_kernel<<<dim3(2304), dim3(256), 0, stream>>>(Qb, Kb, Vt, alignf, gatep, ctx, probs);
}